// Round 8
// baseline (227.586 us; speedup 1.0000x reference)
//
#include <hip/hip_runtime.h>

#define N_NODES 50000
#define N_EDGES 1600000
#define DIM 64
#define NBK 196          // buckets of 256 dst-nodes
#define BIN_BLOCKS 391   // ceil(1.6M / 4096)
#define CSR_CAP 12288    // per-bucket slots = 8 octants x OCT_CAP
#define OCT_CAP 1536     // per-(bucket,octant) slots (mean 1024, +16 sigma)
#define QCAP 3072        // per-quarter slots (mult-16-padded mean ~2560, ~8-sigma margin)
#define G1_BLOCKS 391    // gemm1: 391*128 = 50048 >= 50001 nodes (incl. dummy)
#define NB_AGG8 6250     // aggregate blocks (8 nodes/block; 6250*8 == 50000 exactly)

// f32 -> bf16 round-to-nearest-even
__device__ __forceinline__ unsigned short f2bf(float f) {
    union { float f; unsigned u; } v; v.f = f;
    unsigned r = v.u + 0x7FFF + ((v.u >> 16) & 1);
    return (unsigned short)(r >> 16);
}
__device__ __forceinline__ float bf2f(unsigned short h) {
    union { unsigned u; float f; } v; v.u = ((unsigned)h) << 16;  return v.f;
}
// packed-bf16 halves of a uint -> f32 (low ushort, high ushort)
__device__ __forceinline__ float blo(unsigned u) {
    union { unsigned u; float f; } v; v.u = u << 16; return v.f;
}
__device__ __forceinline__ float bhi(unsigned u) {
    union { unsigned u; float f; } v; v.u = u & 0xFFFF0000u; return v.f;
}

// R21: binning ONLY (R6-proven core, R20 oct-split kept). Split from the old
// fused bin_and_gemm1 so the profiler separates binning from GEMM1 (R20
// post-mortem: fused occupancy 7.8% => tail-bound; suspect is the GEMM path's
// 30K-cycle serial per-thread stream, but fusion hid which path owns the 50us).
__global__ __launch_bounds__(256) void bin_edges(const int* __restrict__ src,
                                                 const int* __restrict__ dst,
                                                 int* __restrict__ bcur,
                                                 int* __restrict__ binned) {
    __shared__ int cnt[NBK];
    __shared__ int lofs[NBK];
    __shared__ int shiftv[NBK];
    __shared__ int sb[256];
    __shared__ int stag[4096];
    __shared__ unsigned char stb[4096];
    int tid = threadIdx.x;

    if (tid < NBK) cnt[tid] = 0;
    __syncthreads();

    int base = blockIdx.x * 4096;
    int oct = blockIdx.x & 7;
    int nedge = N_EDGES - base;
    if (nedge > 4096) nedge = 4096;

    int myb[16], myr[16], myp[16];
#pragma unroll
    for (int i = 0; i < 16; ++i) {
        int e = base + i * 256 + tid;
        myb[i] = -1;
        if (e < N_EDGES) {
            int s = src[e], d = dst[e];
            int b = d >> 8;
            myb[i] = b;
            myp[i] = ((d & 255) << 16) | s;
            myr[i] = atomicAdd(&cnt[b], 1);
        }
    }
    __syncthreads();

    int c = (tid < NBK) ? cnt[tid] : 0;
    sb[tid] = c;
    __syncthreads();
    for (int off = 1; off < 256; off <<= 1) {
        int u = (tid >= off) ? sb[tid - off] : 0;
        __syncthreads();
        sb[tid] += u;
        __syncthreads();
    }
    if (tid < NBK) {
        lofs[tid] = sb[tid] - c;
        if (c) shiftv[tid] = tid * CSR_CAP + oct * OCT_CAP
                           + atomicAdd(&bcur[(tid * 8 + oct) * 16], c) - lofs[tid];
    }
    __syncthreads();

#pragma unroll
    for (int i = 0; i < 16; ++i) {
        if (myb[i] >= 0) {
            int idx = lofs[myb[i]] + myr[i];
            stag[idx] = myp[i];
            stb[idx] = (unsigned char)myb[i];
        }
    }
    __syncthreads();

    for (int i = tid; i < nedge; i += 256)
        binned[i + shiftv[stb[i]]] = stag[i];
}

// R21: T = feat @ W1^T (bf16), restructured for lane-parallelism.
// Old fused GEMM path: each thread computed a 64-wide output row serially
// (4096 dependent FMA + 1024 ds_read per thread, 197 blocks < 1/CU -> tail).
// New: lane = output feature; W1 row held in 16 float4 REGISTERS; X rows
// staged in LDS and read as wave-uniform broadcasts (no bank traffic);
// 4 nodes in flight = 4 independent FMA chains (issue-bound, ~6K cyc/wave).
// 391 blocks x 128 nodes. Writes dummy zero row at node == N_NODES.
__global__ __launch_bounds__(256) void gemm1(const float* __restrict__ X,
                                             const float* __restrict__ W,
                                             unsigned short* __restrict__ T) {
    __shared__ __align__(16) float4 xs[128 * 16];   // 32 KB: 128 node rows
    int tid = threadIdx.x;
    int w = tid >> 6, lane = tid & 63;
    int nbase = blockIdx.x * 128;

    // W row for this lane -> registers (16 KB total, L2-warm across blocks)
    float4 wreg[16];
    const float4* wp = (const float4*)(W + lane * 64);
#pragma unroll
    for (int k4 = 0; k4 < 16; ++k4) wreg[k4] = wp[k4];

    // stage 128 X rows (guard: X has exactly 50000 rows)
    const float4* xg = (const float4*)X;
    for (int L = tid; L < 2048; L += 256) {
        int row = nbase + (L >> 4);
        float4 v = {0.f, 0.f, 0.f, 0.f};
        if (row < N_NODES) v = xg[(size_t)row * 16 + (L & 15)];
        xs[L] = v;
    }
    __syncthreads();

    // wave w: nodes nbase + w*32 .. +31, 4 at a time
    for (int g = 0; g < 8; ++g) {
        int n0 = w * 32 + g * 4;
        float accA = 0.f, accB = 0.f, accC = 0.f, accD = 0.f;
#pragma unroll
        for (int k4 = 0; k4 < 16; ++k4) {
            float4 w4 = wreg[k4];
            float4 xA = xs[(n0 + 0) * 16 + k4];   // wave-uniform -> broadcast
            float4 xB = xs[(n0 + 1) * 16 + k4];
            float4 xC = xs[(n0 + 2) * 16 + k4];
            float4 xD = xs[(n0 + 3) * 16 + k4];
            accA += xA.x * w4.x + xA.y * w4.y + xA.z * w4.z + xA.w * w4.w;
            accB += xB.x * w4.x + xB.y * w4.y + xB.z * w4.z + xB.w * w4.w;
            accC += xC.x * w4.x + xC.y * w4.y + xC.z * w4.z + xC.w * w4.w;
            accD += xD.x * w4.x + xD.y * w4.y + xD.z * w4.z + xD.w * w4.w;
        }
        int gn = nbase + n0;
        unsigned short vA = (gn + 0 == N_NODES) ? (unsigned short)0 : f2bf(accA);
        unsigned short vB = (gn + 1 == N_NODES) ? (unsigned short)0 : f2bf(accB);
        unsigned short vC = (gn + 2 == N_NODES) ? (unsigned short)0 : f2bf(accC);
        unsigned short vD = (gn + 3 == N_NODES) ? (unsigned short)0 : f2bf(accD);
        if (gn + 0 <= N_NODES) T[(size_t)(gn + 0) * 64 + lane] = vA;
        if (gn + 1 <= N_NODES) T[(size_t)(gn + 1) * 64 + lane] = vB;
        if (gn + 2 <= N_NODES) T[(size_t)(gn + 2) * 64 + lane] = vC;
        if (gn + 3 <= N_NODES) T[(size_t)(gn + 3) * 64 + lane] = vD;
    }
}

// R20: one workgroup per (bucket, dst-quarter); scans the bucket's 8 octant
// regions. Pad-fill is per-node tail writes (<=15 each). nodeinfo=
// (pcnt<<23)|pos, pos%16==0, pcnt mult-16.
__global__ __launch_bounds__(256) void build_csr(const int* __restrict__ binned,
                                                 const int* __restrict__ bcur,
                                                 unsigned* __restrict__ nodeinfo,
                                                 unsigned short* __restrict__ csr16) {
    __shared__ int cnt[64], cnt2[64], ofs[64], sb[64];
    __shared__ int mo[8];
    int tid = threadIdx.x;
    int b = blockIdx.x >> 2;
    int q = blockIdx.x & 3;
    int qbase = (b * 4 + q) * QCAP;
    if (tid < 64) { cnt[tid] = 0; cnt2[tid] = 0; }
    if (tid < 8) {
        int m = bcur[(b * 8 + tid) * 16];
        mo[tid] = m > OCT_CAP ? OCT_CAP : m;
    }
    __syncthreads();

    for (int oct = 0; oct < 8; ++oct) {
        int ibase = b * CSR_CAP + oct * OCT_CAP;
        int m = mo[oct];
        for (int i = tid; i < m; i += 256) {
            int dl = (binned[ibase + i] >> 16) & 255;
            if ((dl >> 6) == q) atomicAdd(&cnt[dl & 63], 1);
        }
    }
    __syncthreads();

    int v = 0, myc = 0;
    if (tid < 64) { myc = cnt[tid]; v = (myc + 15) & ~15; sb[tid] = v; }  // mult-16 pad
    __syncthreads();
    for (int off = 1; off < 64; off <<= 1) {
        int u = (tid >= off && tid < 64) ? sb[tid - off] : 0;
        __syncthreads();
        if (tid < 64) sb[tid] += u;
        __syncthreads();
    }
    if (tid < 64) {
        int o = sb[tid] - v;
        ofs[tid] = o;
        int node = (b << 8) + (q << 6) + tid;
        if (node < N_NODES)
            nodeinfo[node] = ((unsigned)v << 23) | (unsigned)(qbase + o);
        for (int i = myc; i < v; ++i)          // pad tail with dummy src
            csr16[qbase + o + i] = (unsigned short)N_NODES;
    }
    __syncthreads();

    for (int oct = 0; oct < 8; ++oct) {
        int ibase = b * CSR_CAP + oct * OCT_CAP;
        int m = mo[oct];
        for (int i = tid; i < m; i += 256) {
            int p = binned[ibase + i];
            int dl = (p >> 16) & 255;
            if ((dl >> 6) == q) {
                int r = atomicAdd(&cnt2[dl & 63], 1);
                csr16[qbase + ofs[dl & 63] + r] = (unsigned short)(p & 0xFFFF);
            }
        }
    }
}

// Accumulate one uint4 (8 bf16 feature values) into 8 f32 accumulators.
#define ACC8(d)                                                     \
    a0 += blo(d.x); a1 += bhi(d.x); a2 += blo(d.y); a3 += bhi(d.y); \
    a4 += blo(d.z); a5 += bhi(d.z); a6 += blo(d.w); a7 += bhi(d.w);

// R17-verbatim agg_fuse1 (proven ~46us). 512 thr / 8 nodes; 4-deep unroll;
// single barrier; W2 epilogue fused.
__global__ __launch_bounds__(512) void agg_fuse1(const unsigned short* __restrict__ T,
                                                 const unsigned short* __restrict__ csr,
                                                 const unsigned* __restrict__ nodeinfo,
                                                 const float* __restrict__ b1,
                                                 const float* __restrict__ W2,
                                                 unsigned short* __restrict__ T2) {
    __shared__ __align__(16) float4 W2t4[1024];     // 16 KB (W2 transposed, lane-striped)
    __shared__ __align__(16) float part[8][8][72];  // 18 KB (per-wave partials; row0 doubles as h)
    int tid = threadIdx.x;
    int w = tid >> 6;
    int lane = tid & 63;
    int g8 = lane >> 3;
    int fs = lane & 7;
    int node = blockIdx.x * 8 + w;

    // stage W2 transposed (read after the single barrier below)
    for (int L4 = tid; L4 < 1024; L4 += 512) {
        int k4 = L4 >> 6, f = L4 & 63;
        W2t4[L4] = *(const float4*)(W2 + f * 64 + k4 * 4);
    }

    // ---- gather-accumulate: 8 rows/load, 4 loads in flight ----
    unsigned info = __builtin_nontemporal_load(nodeinfo + node);
    float bias = b1[lane];
    int pos = (int)(info & 0x7FFFFFu);
    int nch = (int)(info >> 23) >> 3;   // 8-edge chunks, even (pcnt mult 16)
    const unsigned short* ip = csr + pos + g8;
    const uint4* Tp = (const uint4*)T;
    float a0 = 0.f, a1 = 0.f, a2 = 0.f, a3 = 0.f, a4 = 0.f, a5 = 0.f, a6 = 0.f, a7 = 0.f;
    int c = 0;
    for (; c + 4 <= nch; c += 4) {
        int j0 = __builtin_nontemporal_load(ip + c * 8);
        int j1 = __builtin_nontemporal_load(ip + c * 8 + 8);
        int j2 = __builtin_nontemporal_load(ip + c * 8 + 16);
        int j3 = __builtin_nontemporal_load(ip + c * 8 + 24);
        uint4 d0 = Tp[j0 * 8 + fs];
        uint4 d1 = Tp[j1 * 8 + fs];
        uint4 d2 = Tp[j2 * 8 + fs];
        uint4 d3 = Tp[j3 * 8 + fs];
        ACC8(d0) ACC8(d1) ACC8(d2) ACC8(d3)
    }
    if (c < nch) {   // remaining 2 chunks (nch even)
        int j0 = __builtin_nontemporal_load(ip + c * 8);
        int j1 = __builtin_nontemporal_load(ip + c * 8 + 8);
        uint4 d0 = Tp[j0 * 8 + fs];
        uint4 d1 = Tp[j1 * 8 + fs];
        ACC8(d0) ACC8(d1)
    }
    float4 pa = {a0, a1, a2, a3};
    float4 pb = {a4, a5, a6, a7};
    *(float4*)&part[w][g8][fs * 8] = pa;
    *(float4*)&part[w][g8][fs * 8 + 4] = pb;
    __syncthreads();   // covers W2t4 staging (part is wave-private)

    // reduce 8 groups: lane = feature
    float acc = bias;
#pragma unroll
    for (int g = 0; g < 8; ++g) acc += part[w][g][lane];

    // ---- tanh + in-block 64x64 GEMM epilogue (h overlaid in part row 0) ----
    float e = __expf(2.f * acc);
    part[w][0][lane] = 1.f - 2.f / (e + 1.f);   // after all part reads (lockstep wave)

    const float* hrow = &part[w][0][0];
    float tf = 0.f;
#pragma unroll
    for (int k4 = 0; k4 < 16; ++k4) {
        float4 hv = *(const float4*)(hrow + k4 * 4);   // broadcast
        float4 wv = W2t4[k4 * 64 + lane];
        tf += hv.x * wv.x + hv.y * wv.y + hv.z * wv.z + hv.w * wv.w;
    }
    T2[(size_t)node * DIM + lane] = f2bf(tf);

    // zero T2's dummy pad row (block 0 only; agg2 gathers it for padding)
    if (blockIdx.x == 0 && tid < 64)
        T2[(size_t)N_NODES * DIM + tid] = 0;
}

// R17-verbatim agg_out: out = gather-sum(T2) + b2, f32. No barrier.
__global__ __launch_bounds__(512) void agg_out(const unsigned short* __restrict__ T,
                                               const unsigned short* __restrict__ csr,
                                               const unsigned* __restrict__ nodeinfo,
                                               const float* __restrict__ bias,
                                               float* __restrict__ outp) {
    __shared__ __align__(16) float part[8][8][72];  // 18 KB, wave-private
    int tid = threadIdx.x;
    int w = tid >> 6;
    int lane = tid & 63;
    int g8 = lane >> 3;
    int fs = lane & 7;
    int node = blockIdx.x * 8 + w;   // grid*8 == 50000 exactly

    unsigned info = __builtin_nontemporal_load(nodeinfo + node);
    float bv = bias[lane];
    int pos = (int)(info & 0x7FFFFFu);
    int nch = (int)(info >> 23) >> 3;
    const unsigned short* ip = csr + pos + g8;
    const uint4* Tp = (const uint4*)T;
    float a0 = 0.f, a1 = 0.f, a2 = 0.f, a3 = 0.f, a4 = 0.f, a5 = 0.f, a6 = 0.f, a7 = 0.f;
    int c = 0;
    for (; c + 4 <= nch; c += 4) {
        int j0 = __builtin_nontemporal_load(ip + c * 8);
        int j1 = __builtin_nontemporal_load(ip + c * 8 + 8);
        int j2 = __builtin_nontemporal_load(ip + c * 8 + 16);
        int j3 = __builtin_nontemporal_load(ip + c * 8 + 24);
        uint4 d0 = Tp[j0 * 8 + fs];
        uint4 d1 = Tp[j1 * 8 + fs];
        uint4 d2 = Tp[j2 * 8 + fs];
        uint4 d3 = Tp[j3 * 8 + fs];
        ACC8(d0) ACC8(d1) ACC8(d2) ACC8(d3)
    }
    if (c < nch) {
        int j0 = __builtin_nontemporal_load(ip + c * 8);
        int j1 = __builtin_nontemporal_load(ip + c * 8 + 8);
        uint4 d0 = Tp[j0 * 8 + fs];
        uint4 d1 = Tp[j1 * 8 + fs];
        ACC8(d0) ACC8(d1)
    }
    float4 pa = {a0, a1, a2, a3};
    float4 pb = {a4, a5, a6, a7};
    *(float4*)&part[w][g8][fs * 8] = pa;
    *(float4*)&part[w][g8][fs * 8 + 4] = pb;
    // part is wave-private: wave-internal DS ordering suffices, no barrier

    float acc = bv;
#pragma unroll
    for (int g = 0; g < 8; ++g) acc += part[w][g][lane];
    __builtin_nontemporal_store(acc, outp + (size_t)node * DIM + lane);
}

extern "C" void kernel_launch(void* const* d_in, const int* in_sizes, int n_in,
                              void* d_out, int out_size, void* d_ws, size_t ws_size,
                              hipStream_t stream) {
    const float* feat = (const float*)d_in[0];
    const int*   src  = (const int*)d_in[1];
    const int*   dst  = (const int*)d_in[2];
    const float* W1   = (const float*)d_in[3];
    const float* b1   = (const float*)d_in[4];
    const float* W2   = (const float*)d_in[5];
    const float* b2   = (const float*)d_in[6];
    float* out = (float*)d_out;

    // ws layout (~28 MB; harness poisons 256 MB of ws -> plenty)
    int*            binned   = (int*)d_ws;                                // 196*12288 ints
    unsigned short* csr16    = (unsigned short*)(binned + NBK * CSR_CAP); // 784*3072 ushort
    unsigned*       nodeinfo = (unsigned*)(csr16 + NBK * 4 * QCAP);       // 50000
    int*            bcur     = (int*)(nodeinfo + N_NODES);                // 196*8*16 ints
    unsigned short* t        = (unsigned short*)(bcur + NBK * 8 * 16 + 8); // 50001*64 bf16
    unsigned short* t2       = t + (size_t)(N_NODES + 1) * 64;            // 50001*64 bf16

    // ---- binning, layer-1 transform, CSR build (split for isolated counters) ----
    (void)hipMemsetAsync(bcur, 0, NBK * 8 * 16 * sizeof(int), stream);
    bin_edges<<<BIN_BLOCKS, 256, 0, stream>>>(src, dst, bcur, binned);
    gemm1<<<G1_BLOCKS, 256, 0, stream>>>(feat, W1, t);
    build_csr<<<NBK * 4, 256, 0, stream>>>(binned, bcur, nodeinfo, csr16);

    // ---- Layer 1 aggregate + fused layer-2 transform: t2 = tanh(agg+b1)@W2^T ----
    agg_fuse1<<<NB_AGG8, 512, 0, stream>>>(t, csr16, nodeinfo, b1, W2, t2);

    // ---- Layer 2 aggregate: out = agg(t2) + b2, f32 ----
    agg_out<<<NB_AGG8, 512, 0, stream>>>(t2, csr16, nodeinfo, b2, out);
}